// Round 1
// baseline (1526.754 us; speedup 1.0000x reference)
//
#include <hip/hip_runtime.h>
#include <math.h>

#define BB 2048
#define TT 256
#define NI 29
#define HH 128
#define NC 29
#define BROWS 8
#define PADH 132   // padded float stride for 128-wide rows (bank-conflict-free)
#define PADX 36    // padded float stride for 32-wide rows

__device__ __forceinline__ float fast_tanh(float x) {
    float ax = fabsf(x);
    // tanh(x) = sign(x) * (1 - e^{-2|x|}) / (1 + e^{-2|x|});  e^{-2a} = 2^{-2a*log2(e)}
    float e = __builtin_amdgcn_exp2f(ax * -2.885390081777927f);
    float r = (1.0f - e) * __builtin_amdgcn_rcpf(1.0f + e);
    return copysignf(r, x);
}

__device__ __forceinline__ float dot4f(float a, float4 h, float4 w) {
    a = fmaf(h.x, w.x, a);
    a = fmaf(h.y, w.y, a);
    a = fmaf(h.z, w.z, a);
    a = fmaf(h.w, w.w, a);
    return a;
}

template <int IS_DEC>
__launch_bounds__(256, 1)
__global__ void rnn_kernel(const float* __restrict__ xin,   // [B,T,NI]
                           const float* __restrict__ h0p,   // enc: [B,H]; dec: stash base (stride h0_stride)
                           size_t h0_stride,
                           const float* __restrict__ Wih,   // [H,NI]
                           const float* __restrict__ Whh,   // [H,H]
                           const float* __restrict__ bih,   // [H]
                           const float* __restrict__ bhh,   // [H]
                           const float* __restrict__ fcW,   // [NC,H]   (dec only)
                           const float* __restrict__ fcb,   // [NC]    (dec only)
                           float* __restrict__ out)         // enc: stash base; dec: [B,T,NC]
{
    __shared__ __align__(16) float Whh_s[HH][PADH];
    __shared__ __align__(16) float Wih_s[HH][PADX];
    __shared__ __align__(16) float h_s[2][BROWS][PADH];
    __shared__ __align__(16) float x_s[2][BROWS][PADX];
    __shared__ __align__(16) float bias_s[HH];
    __shared__ __align__(16) float fcW_s[NC][PADH];
    __shared__ __align__(16) float fcb_s[32];

    const int tid = threadIdx.x;
    const int b0  = blockIdx.x * BROWS;
    const int r   = tid & 7;
    const int jg  = tid >> 3;            // 0..31
    const int j0 = jg, j1 = jg + 32, j2 = jg + 64, j3 = jg + 96;

    // ---- stage weights to LDS ----
    for (int idx = tid; idx < HH * HH; idx += 256) {
        int j = idx >> 7, i = idx & 127;
        Whh_s[j][i] = Whh[idx];
    }
    for (int idx = tid; idx < HH * NI; idx += 256) {
        int j = idx / NI, i = idx - j * NI;
        Wih_s[j][i] = Wih[idx];
    }
    if (tid < HH) {
        Wih_s[tid][29] = 0.f; Wih_s[tid][30] = 0.f; Wih_s[tid][31] = 0.f;
        bias_s[tid] = bih[tid] + bhh[tid];
    }
    if (tid < 2 * BROWS) {
        int p = tid >> 3, rr = tid & 7;
        x_s[p][rr][29] = 0.f; x_s[p][rr][30] = 0.f; x_s[p][rr][31] = 0.f;
    }
    if (IS_DEC) {
        for (int idx = tid; idx < NC * HH; idx += 256) {
            int c = idx >> 7, i = idx & 127;
            fcW_s[c][i] = fcW[idx];
        }
        if (tid < NC) fcb_s[tid] = fcb[tid];
    }

    // ---- h0 ----
    {
        const float* hrow = h0p + (size_t)(b0 + r) * h0_stride;
        h_s[0][r][j0] = hrow[j0];
        h_s[0][r][j1] = hrow[j1];
        h_s[0][r][j2] = hrow[j2];
        h_s[0][r][j3] = hrow[j3];
    }

    // ---- x_0 ----
    const int  r_x = tid / NI;
    const int  i_x = tid - r_x * NI;
    const bool xv  = tid < BROWS * NI;   // 232 loader threads
    if (xv) x_s[0][r_x][i_x] = xin[((size_t)(b0 + r_x) * TT + 0) * NI + i_x];
    __syncthreads();

    for (int t = 0; t < TT; ++t) {
        const int p = t & 1;

        // prefetch x_{t+1}
        float xn = 0.f;
        if (xv && (t + 1) < TT)
            xn = xin[((size_t)(b0 + r_x) * TT + (t + 1)) * NI + i_x];

        float a0 = bias_s[j0], a1 = bias_s[j1], a2 = bias_s[j2], a3 = bias_s[j3];

        // input projection: 8 i-quads over padded 32
        {
            const float* xr = &x_s[p][r][0];
#pragma unroll
            for (int iq = 0; iq < 8; ++iq) {
                float4 xq = *(const float4*)(xr + iq * 4);
                float4 w0 = *(const float4*)(&Wih_s[j0][iq * 4]);
                float4 w1 = *(const float4*)(&Wih_s[j1][iq * 4]);
                float4 w2 = *(const float4*)(&Wih_s[j2][iq * 4]);
                float4 w3 = *(const float4*)(&Wih_s[j3][iq * 4]);
                a0 = dot4f(a0, xq, w0);
                a1 = dot4f(a1, xq, w1);
                a2 = dot4f(a2, xq, w2);
                a3 = dot4f(a3, xq, w3);
            }
        }
        // recurrence: h_{t-1} @ Whh^T
        {
            const float* hr = &h_s[p][r][0];
#pragma unroll
            for (int iq = 0; iq < 32; ++iq) {
                float4 hq = *(const float4*)(hr + iq * 4);
                float4 w0 = *(const float4*)(&Whh_s[j0][iq * 4]);
                float4 w1 = *(const float4*)(&Whh_s[j1][iq * 4]);
                float4 w2 = *(const float4*)(&Whh_s[j2][iq * 4]);
                float4 w3 = *(const float4*)(&Whh_s[j3][iq * 4]);
                a0 = dot4f(a0, hq, w0);
                a1 = dot4f(a1, hq, w1);
                a2 = dot4f(a2, hq, w2);
                a3 = dot4f(a3, hq, w3);
            }
        }

        float h0n = fast_tanh(a0);
        float h1n = fast_tanh(a1);
        float h2n = fast_tanh(a2);
        float h3n = fast_tanh(a3);
        h_s[p ^ 1][r][j0] = h0n;
        h_s[p ^ 1][r][j1] = h1n;
        h_s[p ^ 1][r][j2] = h2n;
        h_s[p ^ 1][r][j3] = h3n;

        if (xv && (t + 1) < TT) x_s[p ^ 1][r_x][i_x] = xn;

        __syncthreads();

        if (IS_DEC) {
            // fused FC: c = jg, logits[b0+r][t][c]
            const int c = jg;
            if (c < NC) {
                float f = fcb_s[c];
                const float* hn = &h_s[p ^ 1][r][0];
#pragma unroll
                for (int iq = 0; iq < 32; ++iq) {
                    float4 hq = *(const float4*)(hn + iq * 4);
                    float4 wq = *(const float4*)(&fcW_s[c][iq * 4]);
                    f = dot4f(f, hq, wq);
                }
                out[((size_t)(b0 + r) * TT + t) * NC + c] = f;
            }
        }
        // single barrier per step is sufficient:
        //  - next iter writes h_s[p] / x_s[p]; their last reads were before this barrier
        //  - FC reads h_s[p^1], which is not written until after the NEXT barrier
    }

    if (!IS_DEC) {
        // final h (T even -> buffer 0) -> stash into first 128 floats of this row's out region
        float* stash = out + (size_t)(b0 + r) * TT * NC;
        stash[j0] = h_s[0][r][j0];
        stash[j1] = h_s[0][r][j1];
        stash[j2] = h_s[0][r][j2];
        stash[j3] = h_s[0][r][j3];
    }
}

extern "C" void kernel_launch(void* const* d_in, const int* in_sizes, int n_in,
                              void* d_out, int out_size, void* d_ws, size_t ws_size,
                              hipStream_t stream) {
    const float* enc_in  = (const float*)d_in[0];   // [B,T,NI]
    const float* enc_h0  = (const float*)d_in[1];   // [1,B,H]
    const float* dec_in  = (const float*)d_in[2];   // [B,T,NI]
    const float* enc_Wih = (const float*)d_in[3];
    const float* enc_Whh = (const float*)d_in[4];
    const float* enc_bih = (const float*)d_in[5];
    const float* enc_bhh = (const float*)d_in[6];
    const float* dec_Wih = (const float*)d_in[7];
    const float* dec_Whh = (const float*)d_in[8];
    const float* dec_bih = (const float*)d_in[9];
    const float* dec_bhh = (const float*)d_in[10];
    const float* fc_W    = (const float*)d_in[11];
    const float* fc_b    = (const float*)d_in[12];
    float* out = (float*)d_out;

    dim3 grid(BB / BROWS), block(256);

    // Encoder: stash h_T into out (first 128 floats of each row's [T,NC] region);
    // decoder reads it in its prologue, then overwrites every element.
    rnn_kernel<0><<<grid, block, 0, stream>>>(enc_in, enc_h0, (size_t)HH,
                                              enc_Wih, enc_Whh, enc_bih, enc_bhh,
                                              nullptr, nullptr, out);
    rnn_kernel<1><<<grid, block, 0, stream>>>(dec_in, out, (size_t)TT * NC,
                                              dec_Wih, dec_Whh, dec_bih, dec_bhh,
                                              fc_W, fc_b, out);
}

// Round 2
// 452.336 us; speedup vs baseline: 3.3753x; 3.3753x over previous
//
#include <hip/hip_runtime.h>
#include <math.h>

#define TT 256
#define NI 29
#define HH 128
#define NC 29
#define ROWS 16
#define PSTR 168   // fp16 plane stride: 128 h + 32 x(pad) + 8 pad (bank spread)

typedef _Float16 f16x8 __attribute__((ext_vector_type(8)));
typedef _Float16 f16x4 __attribute__((ext_vector_type(4)));
typedef float f32x4 __attribute__((ext_vector_type(4)));

__device__ __forceinline__ float fast_tanh(float x) {
    float ax = fabsf(x);
    float e = __builtin_amdgcn_exp2f(ax * -2.885390081777927f);
    float r = (1.0f - e) * __builtin_amdgcn_rcpf(1.0f + e);
    return copysignf(r, x);
}

// Layout assumptions (standard CDNA4 16x16x32):
//   A[m][k]: m = lane&15, k = (lane>>4)*8 + e   (e = elem 0..7)
//   B[k][n]: n = lane&15, k = (lane>>4)*8 + e
//   C/D:     col = lane&15, row = (lane>>4)*4 + reg   (verified m89/m91)
// We compute W[j,160] @ Hcat^T[160,b]:  A rows = j, B cols = batch row b.
template <int IS_DEC>
__launch_bounds__(512, 1)
__global__ void rnn_mfma(const float* __restrict__ xin,   // [B,T,NI]
                         const float* __restrict__ h0p, long h0s,
                         const float* __restrict__ Wih,   // [H,NI]
                         const float* __restrict__ Whh,   // [H,H]
                         const float* __restrict__ bih,
                         const float* __restrict__ bhh,
                         const float* __restrict__ fcW,   // [NC,H]
                         const float* __restrict__ fcb,
                         float* __restrict__ out)
{
    __shared__ __align__(16) _Float16 planes[2][2][ROWS][PSTR]; // [dbuf][hi/lo][b][i]

    const int tid  = threadIdx.x;
    const int lane = tid & 63;
    const int w    = tid >> 6;          // wave = j-tile 0..7
    const int m    = lane & 15;
    const int g    = lane >> 4;         // 0..3
    const int b0   = blockIdx.x * ROWS;

    // ---- A fragments: rows j = 16w + m of [Whh | Wih], fp16, resident all steps ----
    const int jr = 16 * w + m;
    f16x8 Aw[5];
#pragma unroll
    for (int s = 0; s < 4; ++s) {
        const float* src = Whh + jr * HH + 32 * s + 8 * g;
        float4 v0 = *(const float4*)src;
        float4 v1 = *(const float4*)(src + 4);
        f16x8 a;
        a[0] = (_Float16)v0.x; a[1] = (_Float16)v0.y;
        a[2] = (_Float16)v0.z; a[3] = (_Float16)v0.w;
        a[4] = (_Float16)v1.x; a[5] = (_Float16)v1.y;
        a[6] = (_Float16)v1.z; a[7] = (_Float16)v1.w;
        Aw[s] = a;
    }
    {
        f16x8 a;
#pragma unroll
        for (int e = 0; e < 8; ++e) {
            int i = 8 * g + e;
            float v = (i < NI) ? Wih[jr * NI + i] : 0.f;
            a[e] = (_Float16)v;
        }
        Aw[4] = a;
    }
    float bias[4];
#pragma unroll
    for (int q = 0; q < 4; ++q)
        bias[q] = bih[16 * w + 4 * g + q] + bhh[16 * w + 4 * g + q];

    // ---- FC A fragments (decoder, waves 6 & 7 handle c-tiles 0 & 1) ----
    const int fcw = w - 6;
    f16x8 Afc[4];
    float fcbv[4];
    if (IS_DEC && fcw >= 0) {
        int c = 16 * fcw + m;
#pragma unroll
        for (int s = 0; s < 4; ++s) {
            f16x8 a;
#pragma unroll
            for (int e = 0; e < 8; ++e) {
                int k = 32 * s + 8 * g + e;
                a[e] = (c < NC) ? (_Float16)fcW[c * HH + k] : (_Float16)0.f;
            }
            Afc[s] = a;
        }
#pragma unroll
        for (int q = 0; q < 4; ++q) {
            int c2 = 16 * fcw + 4 * g + q;
            fcbv[q] = (c2 < NC) ? fcb[c2] : 0.f;
        }
    }

    // ---- zero x-pad (i = 128+29..128+31, hi plane, both dbufs) ----
    if (tid < 2 * ROWS * (32 - NI)) {
        int k = tid % (32 - NI);
        int b = (tid / (32 - NI)) % ROWS;
        int d = tid / ((32 - NI) * ROWS);
        planes[d][0][b][HH + NI + k] = (_Float16)0.f;
    }

    // ---- h0 -> planes[0] (split hi/lo fp16) ----
    {
        int b  = (tid * 4) >> 7;
        int i0 = (tid * 4) & 127;
        const float* hr = h0p + (long)(b0 + b) * h0s + i0;
        float4 v = *(const float4*)hr;
        float vv[4] = {v.x, v.y, v.z, v.w};
        f16x4 hi, lo;
#pragma unroll
        for (int e = 0; e < 4; ++e) {
            _Float16 h = (_Float16)vv[e];
            hi[e] = h;
            lo[e] = (_Float16)(vv[e] - (float)h);
        }
        *(f16x4*)&planes[0][0][b][i0] = hi;
        *(f16x4*)&planes[0][1][b][i0] = lo;
    }
    // ---- x_0 (single fp16, hi plane only) ----
    if (tid < ROWS * NI) {
        int b = tid / NI, i = tid % NI;
        planes[0][0][b][HH + i] = (_Float16)xin[((long)(b0 + b) * TT) * NI + i];
    }
    __syncthreads();

    for (int t = 0; t < TT; ++t) {
        const int cur = t & 1, nxt = cur ^ 1;

        // B fragments: n = m (batch row), k = 32s + 8g + e
        f16x8 Bhi[5], Blo[4];
#pragma unroll
        for (int s = 0; s < 5; ++s)
            Bhi[s] = *(const f16x8*)&planes[cur][0][m][32 * s + 8 * g];
#pragma unroll
        for (int s = 0; s < 4; ++s)
            Blo[s] = *(const f16x8*)&planes[cur][1][m][32 * s + 8 * g];

        // recurrence: a = W·h_hi + W·h_lo (+ Wih·x in slice 4)
        f32x4 acc0 = {0.f, 0.f, 0.f, 0.f};
        f32x4 acc1 = {0.f, 0.f, 0.f, 0.f};
#pragma unroll
        for (int s = 0; s < 4; ++s) {
            acc0 = __builtin_amdgcn_mfma_f32_16x16x32_f16(Aw[s], Bhi[s], acc0, 0, 0, 0);
            acc1 = __builtin_amdgcn_mfma_f32_16x16x32_f16(Aw[s], Blo[s], acc1, 0, 0, 0);
        }
        acc0 = __builtin_amdgcn_mfma_f32_16x16x32_f16(Aw[4], Bhi[4], acc0, 0, 0, 0);

        // fused FC on current state (logits for time t-1)
        if (IS_DEC && fcw >= 0 && t > 0) {
            f32x4 fa = {0.f, 0.f, 0.f, 0.f};
#pragma unroll
            for (int s = 0; s < 4; ++s)
                fa = __builtin_amdgcn_mfma_f32_16x16x32_f16(Afc[s], Bhi[s], fa, 0, 0, 0);
#pragma unroll
            for (int q = 0; q < 4; ++q) {
                int c = 16 * fcw + 4 * g + q;
                if (c < NC)
                    out[((long)(b0 + m) * TT + (t - 1)) * NC + c] = fa[q] + fcbv[q];
            }
        }

        // epilogue: tanh, split hi/lo, write h_new (b = m, j = 16w+4g+q)
        {
            f16x4 hi, lo;
#pragma unroll
            for (int q = 0; q < 4; ++q) {
                float h = fast_tanh(acc0[q] + acc1[q] + bias[q]);
                _Float16 hh = (_Float16)h;
                hi[q] = hh;
                lo[q] = (_Float16)(h - (float)hh);
            }
            *(f16x4*)&planes[nxt][0][m][16 * w + 4 * g] = hi;
            *(f16x4*)&planes[nxt][1][m][16 * w + 4 * g] = lo;
        }

        // x_{t+1}
        if (t + 1 < TT && tid < ROWS * NI) {
            int b = tid / NI, i = tid % NI;
            planes[nxt][0][b][HH + i] =
                (_Float16)xin[((long)(b0 + b) * TT + (t + 1)) * NI + i];
        }
        __syncthreads();
    }

    if (IS_DEC) {
        // final FC for t = TT-1 (h_T is in planes[0], TT even)
        if (fcw >= 0) {
            f16x8 Bh[4];
#pragma unroll
            for (int s = 0; s < 4; ++s)
                Bh[s] = *(const f16x8*)&planes[0][0][m][32 * s + 8 * g];
            f32x4 fa = {0.f, 0.f, 0.f, 0.f};
#pragma unroll
            for (int s = 0; s < 4; ++s)
                fa = __builtin_amdgcn_mfma_f32_16x16x32_f16(Afc[s], Bh[s], fa, 0, 0, 0);
#pragma unroll
            for (int q = 0; q < 4; ++q) {
                int c = 16 * fcw + 4 * g + q;
                if (c < NC)
                    out[((long)(b0 + m) * TT + (TT - 1)) * NC + c] = fa[q] + fcbv[q];
            }
        }
    } else {
        // stash h_T (fp32) into first 128 floats of each row's out region
        int b  = (tid * 4) >> 7;
        int i0 = (tid * 4) & 127;
        float4 v;
        v.x = (float)planes[0][0][b][i0 + 0] + (float)planes[0][1][b][i0 + 0];
        v.y = (float)planes[0][0][b][i0 + 1] + (float)planes[0][1][b][i0 + 1];
        v.z = (float)planes[0][0][b][i0 + 2] + (float)planes[0][1][b][i0 + 2];
        v.w = (float)planes[0][0][b][i0 + 3] + (float)planes[0][1][b][i0 + 3];
        *(float4*)(out + (long)(b0 + b) * TT * NC + i0) = v;
    }
}

extern "C" void kernel_launch(void* const* d_in, const int* in_sizes, int n_in,
                              void* d_out, int out_size, void* d_ws, size_t ws_size,
                              hipStream_t stream) {
    const float* enc_in  = (const float*)d_in[0];
    const float* enc_h0  = (const float*)d_in[1];
    const float* dec_in  = (const float*)d_in[2];
    const float* enc_Wih = (const float*)d_in[3];
    const float* enc_Whh = (const float*)d_in[4];
    const float* enc_bih = (const float*)d_in[5];
    const float* enc_bhh = (const float*)d_in[6];
    const float* dec_Wih = (const float*)d_in[7];
    const float* dec_Whh = (const float*)d_in[8];
    const float* dec_bih = (const float*)d_in[9];
    const float* dec_bhh = (const float*)d_in[10];
    const float* fc_W    = (const float*)d_in[11];
    const float* fc_b    = (const float*)d_in[12];
    float* out = (float*)d_out;

    dim3 grid(2048 / ROWS), block(512);

    rnn_mfma<0><<<grid, block, 0, stream>>>(enc_in, enc_h0, (long)HH,
                                            enc_Wih, enc_Whh, enc_bih, enc_bhh,
                                            nullptr, nullptr, out);
    rnn_mfma<1><<<grid, block, 0, stream>>>(dec_in, out, (long)TT * NC,
                                            dec_Wih, dec_Whh, dec_bih, dec_bhh,
                                            fc_W, fc_b, out);
}